// Round 3
// baseline (268.700 us; speedup 1.0000x reference)
//
#include <hip/hip_runtime.h>
#include <hip/hip_bf16.h>

typedef __bf16 bf16;
typedef bf16 bf16x4 __attribute__((ext_vector_type(4)));
typedef bf16 bf16x8 __attribute__((ext_vector_type(8)));
typedef short s16x4 __attribute__((ext_vector_type(4)));
typedef float f32x4 __attribute__((ext_vector_type(4)));

#define MFMA32(A, B, C) __builtin_amdgcn_mfma_f32_16x16x32_bf16(A, B, C, 0, 0, 0)
#define MFMA16(A, B, C) __builtin_amdgcn_mfma_f32_16x16x16bf16_1k(A, B, C, 0, 0, 0)

static constexpr float SCALE = 0.17677669529663687f;  // 1/sqrt(32)
static constexpr float LOG2E = 1.4426950408889634f;

// ---------------- merged prep: convert x, transpose+convert weights, gather bias
// blocks [0,2048): x->bf16 ; [2048,3072): weights ; [3072,7168): bias gather
// bias layout (S^T C-layout!): rbb[h][qt64][kt64][lane64][r4], value =
//   bias[qrow = qt*16 + (lane&15)][key = kt*16 + (lane>>4)*4 + r] * LOG2E
__global__ __launch_bounds__(256) void k_prep(const float* __restrict__ x,
                                              const float* __restrict__ wqkv,
                                              const float* __restrict__ wout,
                                              const float* __restrict__ table,
                                              const int* __restrict__ ridx,
                                              bf16* __restrict__ xb, bf16* __restrict__ wtq,
                                              bf16* __restrict__ wto, bf16* __restrict__ rbb) {
  const int tid = threadIdx.x;
  const int blk = blockIdx.x;
  if (blk < 2048) {
    int t = blk * 256 + tid;
    const float4* s = reinterpret_cast<const float4*>(x) + (size_t)t * 2;
    float4 a = s[0], c = s[1];
    bf16x8 o;
    o[0] = (bf16)a.x; o[1] = (bf16)a.y; o[2] = (bf16)a.z; o[3] = (bf16)a.w;
    o[4] = (bf16)c.x; o[5] = (bf16)c.y; o[6] = (bf16)c.z; o[7] = (bf16)c.w;
    reinterpret_cast<bf16x8*>(xb)[t] = o;
  } else if (blk < 3072) {
    int t = (blk - 2048) * 256 + tid;
    if (t < 196608) {
      int n = t >> 8, k = t & 255;
      wtq[t] = (bf16)wqkv[k * 768 + n];
    } else {
      int t2 = t - 196608;
      int n = t2 >> 8, k = t2 & 255;
      wto[t2] = (bf16)wout[k * 256 + n];
    }
  } else {
    const int bb2 = blk - 3072;           // (qt,kt) tile
    const int qt = bb2 >> 6, kt = bb2 & 63;
    const int r = tid & 3, lane = tid >> 2;
    const int ln = lane & 15, quad = lane >> 4;
    const int qrow = qt * 16 + ln;
    const int key = kt * 16 + quad * 4 + r;
    const int idx = ridx[qrow * 1024 + key];
    const float4* p = reinterpret_cast<const float4*>(table) + idx * 2;
    float4 a = p[0], c = p[1];
    float vals[8] = {a.x, a.y, a.z, a.w, c.x, c.y, c.z, c.w};
    const int base = bb2 * 256 + tid;
#pragma unroll
    for (int h = 0; h < 8; ++h) rbb[h * 1048576 + base] = (bf16)(vals[h] * LOG2E);
  }
}

// -------------------------------------------------- 128x128x(BK=32) bf16 MFMA GEMM
// EPI 0: qkv epilogue -> q(*scale*log2e) [b,h,n,d]; k [b,h,n,d]; v -> vt [b,h,d,n]
// EPI 1: out epilogue -> fp32 out[m][256] + b_out
template <int EPI>
__global__ __launch_bounds__(256) void k_gemm(const bf16* __restrict__ A,
                                              const bf16* __restrict__ Bt,
                                              bf16* __restrict__ q, bf16* __restrict__ kk,
                                              bf16* __restrict__ vt, float* __restrict__ out,
                                              const float* __restrict__ bout) {
  __shared__ __align__(16) bf16 As[128 * 40];
  __shared__ __align__(16) bf16 Bs[128 * 40];
  const int tid = threadIdx.x;
  const int ln = tid & 15, quad = (tid >> 4) & 3, wv = tid >> 6;
  const int wm = (wv >> 1) * 64, wn = (wv & 1) * 64;
  const int m0 = blockIdx.x * 128, n0 = blockIdx.y * 128;
  const int srow = tid >> 2, scg = (tid & 3) * 8;
  f32x4 acc[4][4] = {};

  for (int kt = 0; kt < 256; kt += 32) {
    bf16x8 av0 = *reinterpret_cast<const bf16x8*>(&A[(m0 + srow) * 256 + kt + scg]);
    bf16x8 av1 = *reinterpret_cast<const bf16x8*>(&A[(m0 + 64 + srow) * 256 + kt + scg]);
    bf16x8 bv0 = *reinterpret_cast<const bf16x8*>(&Bt[(n0 + srow) * 256 + kt + scg]);
    bf16x8 bv1 = *reinterpret_cast<const bf16x8*>(&Bt[(n0 + 64 + srow) * 256 + kt + scg]);
    *reinterpret_cast<bf16x8*>(&As[srow * 40 + scg]) = av0;
    *reinterpret_cast<bf16x8*>(&As[(64 + srow) * 40 + scg]) = av1;
    *reinterpret_cast<bf16x8*>(&Bs[srow * 40 + scg]) = bv0;
    *reinterpret_cast<bf16x8*>(&Bs[(64 + srow) * 40 + scg]) = bv1;
    __syncthreads();
    bf16x8 af[4], bfr[4];
#pragma unroll
    for (int i = 0; i < 4; ++i)
      af[i] = *reinterpret_cast<const bf16x8*>(&As[(wm + i * 16 + ln) * 40 + quad * 8]);
#pragma unroll
    for (int i = 0; i < 4; ++i)
      bfr[i] = *reinterpret_cast<const bf16x8*>(&Bs[(wn + i * 16 + ln) * 40 + quad * 8]);
#pragma unroll
    for (int i = 0; i < 4; ++i)
#pragma unroll
      for (int j = 0; j < 4; ++j) acc[i][j] = MFMA32(af[i], bfr[j], acc[i][j]);
    __syncthreads();
  }

  if (EPI == 0) {
    const int colbase = n0 + wn;
    const int seg = colbase >> 8;
    const int cb = colbase & 255;
    const float mul = (seg == 0) ? SCALE * LOG2E : 1.0f;
#pragma unroll
    for (int i = 0; i < 4; ++i) {
      const int gm = m0 + wm + i * 16 + quad * 4;
      const int b = gm >> 10;
#pragma unroll
      for (int j = 0; j < 4; ++j) {
        const int gc = cb + j * 16 + ln;
        const int h = gc >> 5, d = gc & 31;
#pragma unroll
        for (int r = 0; r < 4; ++r) {
          const int nseq = (gm + r) & 1023;
          if (seg == 2) {
            vt[(b * 8 + h) * 32768 + d * 1024 + nseq] = (bf16)acc[i][j][r];
          } else {
            bf16* dst = (seg == 0) ? q : kk;
            dst[(b * 8 + h) * 32768 + nseq * 32 + d] = (bf16)(acc[i][j][r] * mul);
          }
        }
      }
    }
  } else {
#pragma unroll
    for (int j = 0; j < 4; ++j) {
      const int gc = n0 + wn + j * 16 + ln;
      const float bb = bout[gc];
#pragma unroll
      for (int i = 0; i < 4; ++i) {
        const int gm = m0 + wm + i * 16 + quad * 4;
#pragma unroll
        for (int r = 0; r < 4; ++r) out[(size_t)(gm + r) * 256 + gc] = acc[i][j][r] + bb;
      }
    }
  }
}

// ----------------------------------------------------------------- flash attention
// Zero-LDS flash. QK computed operand-swapped (S^T = K*Q^T): the C-layout output
// (lane holds S^T[key=quad*4+r][qrow=ln]) IS the A-operand layout of the K=16
// MFMA (A[m=ln][k=quad*4+j], r==j), so P feeds PV directly from registers —
// no LDS round trip, no barrier, no transform. V B-frags are contiguous 8B
// loads from vt[b,h,d,n]. Bias pre-gathered in S^T C-layout seeds the QK acc.
// Out-of-range prefetches on the last iter land in allocated d_ws (unused).
__global__ __launch_bounds__(256) void k_flash(const bf16* __restrict__ qs,
                                               const bf16* __restrict__ ks,
                                               const bf16* __restrict__ vtg,
                                               const bf16* __restrict__ rbb,
                                               bf16* __restrict__ ao) {
  const int tid = threadIdx.x;
  const int lane = tid & 63;
  const int ln = lane & 15, quad = lane >> 4, wv = tid >> 6;
  const int bh = blockIdx.x >> 4;
  const int b = bh >> 3, h = bh & 7;
  const int qtw = (blockIdx.x & 15) * 4 + wv;  // 16-row q-tile index [0,64)
  const int q0 = qtw * 16;
  const bf16* qb = qs + bh * 32768;
  const bf16* kb = ks + bh * 32768;
  const bf16* vb = vtg + bh * 32768;
  const bf16* bbias = rbb + h * 1048576 + qtw * 16384 + lane * 4;  // + kt16*256

  // Q as B-operand: B[k=d=quad*8+j][n=qrow=ln] = Q[q0+ln][quad*8+j]
  const bf16x8 qfrag = *reinterpret_cast<const bf16x8*>(&qb[(q0 + ln) * 32 + quad * 8]);

  f32x4 acc00 = {0.f, 0.f, 0.f, 0.f}, acc01 = {0.f, 0.f, 0.f, 0.f};
  f32x4 acc10 = {0.f, 0.f, 0.f, 0.f}, acc11 = {0.f, 0.f, 0.f, 0.f};
  float lsum = 0.f;

  bf16x8 kf[2][4];
  bf16x4 cb[2][4];
#pragma unroll
  for (int nt = 0; nt < 4; ++nt) {
    kf[0][nt] = *reinterpret_cast<const bf16x8*>(&kb[(nt * 16 + ln) * 32 + quad * 8]);
    cb[0][nt] = *reinterpret_cast<const bf16x4*>(&bbias[nt * 256]);
  }

#define STEP(CUR, NXT, IT)                                                                 \
  {                                                                                        \
    const int k0 = (IT) * 64;                                                              \
    s16x4 vf0[4], vf1[4];                                                                  \
    _Pragma("unroll") for (int nt = 0; nt < 4; ++nt) {                                     \
      vf0[nt] = *reinterpret_cast<const s16x4*>(&vb[ln * 1024 + k0 + nt * 16 + quad * 4]); \
      vf1[nt] =                                                                            \
          *reinterpret_cast<const s16x4*>(&vb[(16 + ln) * 1024 + k0 + nt * 16 + quad * 4]);\
    }                                                                                      \
    f32x4 s[4];                                                                            \
    _Pragma("unroll") for (int nt = 0; nt < 4; ++nt) {                                     \
      f32x4 c;                                                                             \
      _Pragma("unroll") for (int e = 0; e < 4; ++e) c[e] = (float)cb[CUR][nt][e];          \
      s[nt] = MFMA32(kf[CUR][nt], qfrag, c);                                               \
    }                                                                                      \
    _Pragma("unroll") for (int nt = 0; nt < 4; ++nt) {                                     \
      kf[NXT][nt] =                                                                        \
          *reinterpret_cast<const bf16x8*>(&kb[(k0 + 64 + nt * 16 + ln) * 32 + quad * 8]); \
      cb[NXT][nt] = *reinterpret_cast<const bf16x4*>(&bbias[((IT) * 4 + 4 + nt) * 256]);   \
    }                                                                                      \
    s16x4 p[4];                                                                            \
    _Pragma("unroll") for (int nt = 0; nt < 4; ++nt) {                                     \
      bf16x4 t;                                                                            \
      _Pragma("unroll") for (int e = 0; e < 4; ++e) {                                      \
        s[nt][e] = __builtin_amdgcn_exp2f(s[nt][e]);                                       \
        t[e] = (bf16)s[nt][e];                                                             \
      }                                                                                    \
      lsum += (s[nt][0] + s[nt][1]) + (s[nt][2] + s[nt][3]);                               \
      p[nt] = __builtin_bit_cast(s16x4, t);                                                \
    }                                                                                      \
    acc00 = MFMA16(p[0], vf0[0], acc00);                                                   \
    acc10 = MFMA16(p[0], vf1[0], acc10);                                                   \
    acc01 = MFMA16(p[1], vf0[1], acc01);                                                   \
    acc11 = MFMA16(p[1], vf1[1], acc11);                                                   \
    acc00 = MFMA16(p[2], vf0[2], acc00);                                                   \
    acc10 = MFMA16(p[2], vf1[2], acc10);                                                   \
    acc01 = MFMA16(p[3], vf0[3], acc01);                                                   \
    acc11 = MFMA16(p[3], vf1[3], acc11);                                                   \
  }

#pragma unroll 1
  for (int it2 = 0; it2 < 8; ++it2) {
    STEP(0, 1, 2 * it2)
    STEP(1, 0, 2 * it2 + 1)
  }
#undef STEP

  // total row sum for qrow=ln: local partial covers this quad's keys; combine quads
  lsum += __shfl_xor(lsum, 16, 64);
  lsum += __shfl_xor(lsum, 32, 64);

  f32x4 a0 = acc00 + acc01;  // O[qrow=quad*4+r][d=ln]
  f32x4 a1 = acc10 + acc11;  // O[qrow=quad*4+r][d=16+ln]
#pragma unroll
  for (int r = 0; r < 4; ++r) {
    const float inv = __builtin_amdgcn_rcpf(__shfl(lsum, quad * 4 + r, 64));
    const int row = q0 + quad * 4 + r;
    bf16* po = &ao[(size_t)(b * 1024 + row) * 256 + h * 32 + ln];
    po[0] = (bf16)(a0[r] * inv);
    po[16] = (bf16)(a1[r] * inv);
  }
}

// ---------------------------------------------------------------------- launcher
extern "C" void kernel_launch(void* const* d_in, const int* in_sizes, int n_in,
                              void* d_out, int out_size, void* d_ws, size_t ws_size,
                              hipStream_t stream) {
  const float* x = (const float*)d_in[0];
  const float* wqkv = (const float*)d_in[1];
  const float* wout = (const float*)d_in[2];
  const float* bout = (const float*)d_in[3];
  const float* btab = (const float*)d_in[4];
  const int* ridx = (const int*)d_in[5];
  float* out = (float*)d_out;

  char* ws = (char*)d_ws;
  bf16* xb  = (bf16*)(ws + 0);           // 8 MB   [16384][256]
  bf16* wtq = (bf16*)(ws + 8388608);     // 384 KB
  bf16* wto = (bf16*)(ws + 8781824);     // 128 KB
  bf16* q   = (bf16*)(ws + 8912896);     // 8 MB   [b,h,n,d] (pre-scaled scale*log2e)
  bf16* k   = (bf16*)(ws + 17301504);    // 8 MB   [b,h,n,d]
  bf16* vt  = (bf16*)(ws + 25690112);    // 8 MB   [b,h,d,n]
  bf16* rb  = (bf16*)(ws + 34078720);    // 16 MB  S^T C-layout bias tiles (*log2e)
  bf16* ao  = (bf16*)(ws + 50855936);    // 8 MB   [16384][256]

  k_prep<<<7168, 256, 0, stream>>>(x, wqkv, wout, btab, ridx, xb, wtq, wto, rb);
  k_gemm<0><<<dim3(128, 6), 256, 0, stream>>>(xb, wtq, q, k, vt, nullptr, nullptr);
  k_flash<<<2048, 256, 0, stream>>>(q, k, vt, rb, ao);
  k_gemm<1><<<dim3(128, 2), 256, 0, stream>>>(ao, wto, nullptr, nullptr, nullptr, out, bout);
}